// Round 7
// baseline (743.454 us; speedup 1.0000x reference)
//
#include <hip/hip_runtime.h>
#include <math.h>

#define BATCH 512
#define SEQ   200
#define TOK   10
#define EMB   25
#define XPAD  28    // xs row stride (floats): 112 B, 16B-aligned rows
#define HID   64
#define G3    192   // 3*HID
#define ATILE 8     // attn phase-1 s-tile
#define EMB_BLOCKS ((BATCH * SEQ) / 8)   // 12800
#define UT2_BLOCKS 96                    // 2 dirs x 3 gates x 16 chunks

__device__ __forceinline__ float fast_sigmoid(float t) {
    float e = __expf(-t);
    return __builtin_amdgcn_rcpf(1.f + e);
}
__device__ __forceinline__ float fast_tanh(float t) {
    float e2 = __expf(2.f * t);
    return 1.f - 2.f * __builtin_amdgcn_rcpf(e2 + 1.f);
}

// Barrier that orders LDS producer->consumer WITHOUT draining vmcnt:
// writer-side ds ops complete (lgkmcnt(0)), then s_barrier. The global
// out-store stays fire-and-forget (no vmcnt(0) on the critical path).
#define LDS_BARRIER() do {                                   \
    asm volatile("s_waitcnt lgkmcnt(0)" ::: "memory");       \
    __builtin_amdgcn_s_barrier();                            \
    asm volatile("" ::: "memory");                           \
} while (0)

// ---------------------------------------------------------------------------
// Kernel 1: masked-mean embedding bag + step mask. The last UT2_BLOCKS
// blocks instead repack U into chunk-major ut2 for the GRU:
//   ut2[((dir*3+g)*16+c)*256 + j*4 + q] = U[(4c+q)*G3 + g*64 + j]
// so a GRU wave reads its 64 weights as 16 coalesced float4 loads.
// ---------------------------------------------------------------------------
__global__ __launch_bounds__(256) void emb_mean_kernel(
    const int* __restrict__ ids_g, const float* __restrict__ emb,
    const float* __restrict__ U_f, const float* __restrict__ U_b,
    float* __restrict__ x, float* __restrict__ mask, float* __restrict__ ut2)
{
    if (blockIdx.x >= EMB_BLOCKS) {
        const int eb = blockIdx.x - EMB_BLOCKS;   // 0..95 = (dir*3+g)*16+c
        const int dir = eb / 48;
        const int g   = (eb % 48) / 16;
        const int c   = eb % 16;
        const int t   = threadIdx.x;
        const int jj  = t >> 2, q = t & 3;
        const float* U = dir ? U_b : U_f;
        ut2[(size_t)eb * 256 + t] = U[(size_t)(4 * c + q) * G3 + g * HID + jj];
        return;
    }
    int grp  = blockIdx.x * 8 + (threadIdx.x >> 5);
    int lane = threadIdx.x & 31;
    const int* ids = ids_g + (size_t)grp * TOK;
    float acc = 0.f;
    int cnt = 0;
    #pragma unroll
    for (int t = 0; t < TOK; t++) {
        int id = ids[t];
        if (id != 0) {
            cnt++;
            if (lane < EMB) acc += emb[(size_t)id * EMB + lane];
        }
    }
    if (lane < EMB)
        x[(size_t)grp * EMB + lane] = cnt ? acc / (float)cnt : 0.f;
    if (lane == 0)
        mask[grp] = (ids[0] != 0) ? 1.f : 0.f;
}

// ---------------------------------------------------------------------------
// Kernel 2: GRU scan v3 — 3 waves (z,r,h-combine) x NB=2 BATCHES per block.
// Post-mortem model (7 data points): VGPR grant is 64 for 3-wave blocks;
// weights re-stream from L1 every step. 210 KB/step/CU at ~86 B/cy = the
// 203us wall (half the VALU was reload addressing). Fix = amortize, not
// fight: each weight fetch feeds TWO batches' FMAs, and the repacked ut2
// layout turns 64 strided dword loads into 16 coalesced float4 loads with
// near-zero address math. Weight traffic/CU-step: 210 KB -> 96 KB.
// The 'up' pointer is pinned opaque per-iteration so LICM can neither
// hoist the 16 loads (64-reg hoist -> spill chaos) nor sink anything else.
// Sync structure unchanged: 2 lgkm-only barriers/step, fire-and-forget
// global stores, x-projection for step+1 in the combine window.
// Grid: 512 blocks = dir (bid>>8) x 256 batch-pairs. 2 blocks/CU (48 KB LDS).
// ---------------------------------------------------------------------------

#define W_LIST(M) \
  M(0)  M(1)  M(2)  M(3)  M(4)  M(5)  M(6)  M(7)  \
  M(8)  M(9)  M(10) M(11) M(12) M(13) M(14) M(15) \
  M(16) M(17) M(18) M(19) M(20) M(21) M(22) M(23) M(24)

#define DECL_W(i) const float w##i = W[(i) * G3 + col];

#define X4(q, i0, i1, i2, i3) {                   \
    const float4 xv = xr4[q];                     \
    p0 = fmaf(xv.x, w##i0, p0);                   \
    p1 = fmaf(xv.y, w##i1, p1);                   \
    p2 = fmaf(xv.z, w##i2, p2);                   \
    p3 = fmaf(xv.w, w##i3, p3); }

// x-projection of row XR (float* into xs, stride-XPAD row, 16B aligned)
#define XPROJ(P, XR) do {                                         \
    const float4* xr4 = (const float4*)(XR);                      \
    float p0 = bx, p1 = 0.f, p2 = 0.f, p3 = 0.f;                  \
    X4(0, 0, 1, 2, 3)   X4(1, 4, 5, 6, 7)   X4(2, 8, 9, 10, 11)  \
    X4(3, 12, 13, 14, 15) X4(4, 16, 17, 18, 19) X4(5, 20, 21, 22, 23) \
    p0 = fmaf((XR)[24], w24, p0);                                 \
    P = (p0 + p1) + (p2 + p3);                                    \
} while (0)

__global__ __launch_bounds__(192, 2) void gru_kernel(
    const float* __restrict__ xg, const float* __restrict__ maskg,
    const float* __restrict__ W_f, const float* __restrict__ b_f,
    const float* __restrict__ W_b, const float* __restrict__ b_b,
    const float* __restrict__ ut2,
    float* __restrict__ outg, float* __restrict__ hT)
{
    const int bid  = blockIdx.x;
    const int dir  = bid >> 8;         // 0 = forward, 1 = backward
    const int pair = bid & 255;
    const int b0   = pair * 2;
    const int b1   = b0 + 1;
    const int tid  = threadIdx.x;
    const int g    = tid >> 6;         // gate: 0=z, 1=r, 2=h(+combine)
    const int j    = tid & 63;         // hidden column

    const float* W    = dir ? W_b : W_f;
    const float* bias = dir ? b_b : b_f;
    const int col = g * HID + j;

    // resident: 25 W regs + biases (demand ~60 total, under the 64 grant)
    W_LIST(DECL_W)
    const float bx = bias[col];        // input-projection bias
    const float br = bias[G3 + col];   // recurrent bias

    __shared__ __align__(16) float xs[2][SEQ * XPAD];   // 44.8 KB
    __shared__ float ms[2][SEQ];
    __shared__ __align__(16) float hs[2][HID];
    __shared__ float zs[2][HID];
    __shared__ float rs[2][HID];

    // cooperative staging for both batches (coalesced, padded LDS rows)
    for (int i = tid; i < SEQ * EMB; i += 192) {
        int s_ = i / EMB;
        int e_ = i - s_ * EMB;
        xs[0][s_ * XPAD + e_] = xg[(size_t)b0 * (SEQ * EMB) + i];
        xs[1][s_ * XPAD + e_] = xg[(size_t)b1 * (SEQ * EMB) + i];
    }
    for (int i = tid; i < SEQ; i += 192) {
        ms[0][i] = maskg[(size_t)b0 * SEQ + i];
        ms[1][i] = maskg[(size_t)b1 * SEQ + i];
    }
    if (tid < HID) { hs[0][tid] = 0.f; hs[1][tid] = 0.f; }
    __syncthreads();   // staging barrier (vmcnt drain fine, once)

    // per-(dir,gate,lane) chunk-major weight base: chunk c at +c*1024 B
    const float* ub = ut2 + (size_t)(dir * 3 + g) * 16 * 256 + j * 4;

    float h0 = 0.f, h1 = 0.f;          // running h (combiner wave only)
    float* ob0 = outg + (size_t)b0 * SEQ * (2 * HID) + dir * HID + j;
    float* ob1 = outg + (size_t)b1 * SEQ * (2 * HID) + dir * HID + j;

    // software-pipelined x-projection for step 0
    float p0x, p1x;
    {
        const int s0 = dir ? (SEQ - 1) : 0;
        XPROJ(p0x, &xs[0][s0 * XPAD]);
        XPROJ(p1x, &xs[1][s0 * XPAD]);
    }

    for (int step = 0; step < SEQ; step++) {
        const int s = dir ? (SEQ - 1 - step) : step;

        const float4* h40 = (const float4*)hs[0];
        const float4* h41 = (const float4*)hs[1];
        const float* up = ub;
        asm volatile("" : "+v"(up));   // opaque: u-loads stay in-loop, streamed

        // recurrent dots for BOTH batches off one weight stream
        float a0 = br, a1 = 0.f, a2 = 0.f, a3 = 0.f;
        float c0 = br, c1 = 0.f, c2 = 0.f, c3 = 0.f;
        #pragma unroll
        for (int c = 0; c < 16; c++) {
            const float4 u  = *(const float4*)(up + c * 256);
            const float4 v0 = h40[c];
            const float4 v1 = h41[c];
            a0 = fmaf(v0.x, u.x, a0);  a1 = fmaf(v0.y, u.y, a1);
            a2 = fmaf(v0.z, u.z, a2);  a3 = fmaf(v0.w, u.w, a3);
            c0 = fmaf(v1.x, u.x, c0);  c1 = fmaf(v1.y, u.y, c1);
            c2 = fmaf(v1.z, u.z, c2);  c3 = fmaf(v1.w, u.w, c3);
        }
        const float a = (a0 + a1) + (a2 + a3);
        const float c = (c0 + c1) + (c2 + c3);

        if (g == 0) {
            zs[0][j] = fast_sigmoid(p0x + a);
            zs[1][j] = fast_sigmoid(p1x + c);
        } else if (g == 1) {
            rs[0][j] = fast_sigmoid(p0x + a);
            rs[1][j] = fast_sigmoid(p1x + c);
        }

        LDS_BARRIER();   // A: zs/rs visible to the combiner

        if (g == 2) {
            float r0 = rs[0][j], z0 = zs[0][j];
            float hh0 = fast_tanh(p0x + r0 * a);
            float hn0 = z0 * h0 + (1.f - z0) * hh0;
            hn0 = (ms[0][s] != 0.f) ? hn0 : h0;
            h0 = hn0;
            hs[0][j] = hn0;
            ob0[(size_t)s * (2 * HID)] = hn0;    // fire-and-forget
            float r1 = rs[1][j], z1 = zs[1][j];
            float hh1 = fast_tanh(p1x + r1 * c);
            float hn1 = z1 * h1 + (1.f - z1) * hh1;
            hn1 = (ms[1][s] != 0.f) ? hn1 : h1;
            h1 = hn1;
            hs[1][j] = hn1;
            ob1[(size_t)s * (2 * HID)] = hn1;    // fire-and-forget
        }

        // x-projection for the NEXT step (h-independent): fills the window
        {
            const int sn  = dir ? (SEQ - 2 - step) : (step + 1);
            const int snc = (step + 1 < SEQ) ? sn : s;   // clamp (unused last iter)
            XPROJ(p0x, &xs[0][snc * XPAD]);
            XPROJ(p1x, &xs[1][snc * XPAD]);
        }

        LDS_BARRIER();   // B: new hs visible to all waves
    }
    if (g == 2 && dir == 0) {
        hT[(size_t)b0 * HID + j] = h0;
        hT[(size_t)b1 * HID + j] = h1;
    }
}

// ---------------------------------------------------------------------------
// Kernel 3: attention pooling v2 (unchanged from round 6).
// ---------------------------------------------------------------------------

#define WK_LIST(M) \
  M(0)  M(1)  M(2)  M(3)  M(4)  M(5)  M(6)  M(7)  \
  M(8)  M(9)  M(10) M(11) M(12) M(13) M(14) M(15) \
  M(16) M(17) M(18) M(19) M(20) M(21) M(22) M(23) \
  M(24) M(25) M(26) M(27) M(28) M(29) M(30) M(31)

#define DECL_WK(t) const float wk##t = W_k[(size_t)(32 * wave + (t)) * HID + lane];

#define KF4(q, t0, t1, t2, t3) {                  \
    const float4 ov = o4[q];                      \
    acc0 = fmaf(ov.x, wk##t0, acc0);              \
    acc1 = fmaf(ov.y, wk##t1, acc1);              \
    acc0 = fmaf(ov.z, wk##t2, acc0);              \
    acc1 = fmaf(ov.w, wk##t3, acc1); }

__global__ __launch_bounds__(256) void attn_kernel(
    const float* __restrict__ outg, const float* __restrict__ maskg,
    const float* __restrict__ hT,
    const float* __restrict__ W_k, const float* __restrict__ b_k,
    const float* __restrict__ W_q, const float* __restrict__ b_q,
    const float* __restrict__ W_e, const float* __restrict__ b_e,
    float* __restrict__ ctx)
{
    const int b    = blockIdx.x;
    const int tid  = threadIdx.x;
    const int wave = tid >> 6;
    const int lane = tid & 63;

    __shared__ float qs[HID];
    __shared__ float es[SEQ];
    __shared__ __align__(16) float kp[ATILE][4][HID];
    __shared__ __align__(16) float psum[4][2 * HID];

    WK_LIST(DECL_WK)

    const float bkj = b_k[lane];
    const float wej = W_e[lane];
    const float be  = b_e[0];

    if (tid < HID) {
        float q = b_q[tid];
        const float* hrow = hT + (size_t)b * HID;
        #pragma unroll 8
        for (int i = 0; i < HID; i++) q = fmaf(hrow[i], W_q[i * HID + tid], q);
        qs[tid] = q;
    }
    __syncthreads();
    const float qj = qs[lane];

    for (int s0 = 0; s0 < SEQ; s0 += ATILE) {
        #pragma unroll 2
        for (int t = 0; t < ATILE; t++) {
            const int s = s0 + t;
            const float4* o4 = (const float4*)(outg +
                ((size_t)b * SEQ + s) * (2 * HID) + 32 * wave);
            float acc0 = 0.f, acc1 = 0.f;
            KF4(0,  0,  1,  2,  3)  KF4(1,  4,  5,  6,  7)
            KF4(2,  8,  9, 10, 11)  KF4(3, 12, 13, 14, 15)
            KF4(4, 16, 17, 18, 19)  KF4(5, 20, 21, 22, 23)
            KF4(6, 24, 25, 26, 27)  KF4(7, 28, 29, 30, 31)
            kp[t][wave][lane] = acc0 + acc1;
        }
        __syncthreads();
        #pragma unroll
        for (int t = wave; t < ATILE; t += 4) {
            const int s = s0 + t;
            float k = (kp[t][0][lane] + kp[t][1][lane]) +
                      (kp[t][2][lane] + kp[t][3][lane]);
            float v = tanhf(k + bkj + qj) * wej;
            #pragma unroll
            for (int off = 32; off > 0; off >>= 1) v += __shfl_xor(v, off);
            if (lane == 0) {
                float pen = (maskg[(size_t)b * SEQ + s] != 0.f) ? 0.f : -1e9f;
                es[s] = v + be + pen;
            }
        }
        __syncthreads();
    }

    if (tid < 64) {
        float mx = -1e30f;
        for (int s2 = tid; s2 < SEQ; s2 += 64) mx = fmaxf(mx, es[s2]);
        #pragma unroll
        for (int off = 32; off > 0; off >>= 1) mx = fmaxf(mx, __shfl_xor(mx, off));
        float sum = 0.f;
        for (int s2 = tid; s2 < SEQ; s2 += 64) {
            float w = expf(es[s2] - mx);
            es[s2] = w;
            sum += w;
        }
        #pragma unroll
        for (int off = 32; off > 0; off >>= 1) sum += __shfl_xor(sum, off);
        float inv = 1.f / sum;
        for (int s2 = tid; s2 < SEQ; s2 += 64) es[s2] *= inv;
    }
    __syncthreads();

    {
        float a0 = 0.f, a1 = 0.f;
        #pragma unroll 2
        for (int s2 = wave; s2 < SEQ; s2 += 4) {
            const float2 v = *(const float2*)(outg +
                ((size_t)b * SEQ + s2) * (2 * HID) + lane * 2);
            const float wsc = es[s2];
            a0 = fmaf(wsc, v.x, a0);
            a1 = fmaf(wsc, v.y, a1);
        }
        psum[wave][2 * lane]     = a0;
        psum[wave][2 * lane + 1] = a1;
    }
    __syncthreads();
    if (tid < 2 * HID) {
        ctx[(size_t)b * (2 * HID) + tid] =
            (psum[0][tid] + psum[1][tid]) + (psum[2][tid] + psum[3][tid]);
    }
}

// ---------------------------------------------------------------------------
extern "C" void kernel_launch(void* const* d_in, const int* in_sizes, int n_in,
                              void* d_out, int out_size, void* d_ws, size_t ws_size,
                              hipStream_t stream) {
    const int*   ids = (const int*)  d_in[0];
    const float* emb = (const float*)d_in[1];
    const float* W_f = (const float*)d_in[2];
    const float* U_f = (const float*)d_in[3];
    const float* b_f = (const float*)d_in[4];
    const float* W_b = (const float*)d_in[5];
    const float* U_b = (const float*)d_in[6];
    const float* b_b = (const float*)d_in[7];
    const float* W_k = (const float*)d_in[8];
    const float* b_k = (const float*)d_in[9];
    const float* W_q = (const float*)d_in[10];
    const float* b_q = (const float*)d_in[11];
    const float* W_e = (const float*)d_in[12];
    const float* b_e = (const float*)d_in[13];

    float* ws   = (float*)d_ws;
    // workspace layout (floats):
    //   x    : [0, 2'560'000)                 (B*S*E)
    //   mask : [2'560'000, 2'662'400)         (B*S)
    //   out  : [2'662'400, 15'769'600)        (B*S*2H)
    //   hT   : [15'769'600, 15'802'368)       (B*H)
    //   ut2  : [15'802'368, 15'826'944)       (2*3*16*256 repacked U)
    float* x    = ws;
    float* mask = ws + 2560000;
    float* out  = ws + 2662400;
    float* hT   = ws + 15769600;
    float* ut2  = ws + 15802368;

    emb_mean_kernel<<<EMB_BLOCKS + UT2_BLOCKS, 256, 0, stream>>>(
        ids, emb, U_f, U_b, x, mask, ut2);
    gru_kernel<<<512, 192, 0, stream>>>(x, mask, W_f, b_f, W_b, b_b, ut2,
                                        out, hT);
    attn_kernel<<<BATCH, 256, 0, stream>>>(out, mask, hT, W_k, b_k,
                                           W_q, b_q, W_e, b_e, (float*)d_out);
}

// Round 8
// 544.353 us; speedup vs baseline: 1.3658x; 1.3658x over previous
//
#include <hip/hip_runtime.h>
#include <math.h>

#define BATCH 512
#define SEQ   200
#define TOK   10
#define EMB   25
#define XPAD  28    // xs row stride (floats): 112 B, 16B-aligned rows
#define HID   64
#define G3    192   // 3*HID
#define ATILE 8     // attn phase-1 s-tile
#define EMB_BLOCKS ((BATCH * SEQ) / 8)   // 12800
#define RPK_BLOCKS 108                   // 96 U-repack + 12 W-repack

__device__ __forceinline__ float fast_sigmoid(float t) {
    float e = __expf(-t);
    return __builtin_amdgcn_rcpf(1.f + e);
}
__device__ __forceinline__ float fast_tanh(float t) {
    float e2 = __expf(2.f * t);
    return 1.f - 2.f * __builtin_amdgcn_rcpf(e2 + 1.f);
}

// Barrier that orders LDS producer->consumer WITHOUT draining vmcnt:
// writer-side ds ops complete (lgkmcnt(0)), then s_barrier. The global
// out-store stays fire-and-forget (no vmcnt(0) on the critical path).
#define LDS_BARRIER() do {                                   \
    asm volatile("s_waitcnt lgkmcnt(0)" ::: "memory");       \
    __builtin_amdgcn_s_barrier();                            \
    asm volatile("" ::: "memory");                           \
} while (0)

// ---------------------------------------------------------------------------
// Kernel 1: masked-mean embedding bag + step mask. Trailing blocks repack
// U and W into per-(dir,gate,khalf) coalesced slices for the GRU:
//  ut2[slice][c][j][q] (slice=(dir*3+g)*2+kh, c<8) = U[(kh*32+4c+q)*G3 + g*64+j]
//  wt2[slice][t][j]   (t<13, t>=ne zero-padded)    = W[(kh*12+t)*G3 + g*64+j]
// so a GRU wave streams its weights as 8 float4 + 13 dword coalesced loads.
// ---------------------------------------------------------------------------
__global__ __launch_bounds__(256) void emb_mean_kernel(
    const int* __restrict__ ids_g, const float* __restrict__ emb,
    const float* __restrict__ U_f, const float* __restrict__ U_b,
    const float* __restrict__ W_f, const float* __restrict__ W_b,
    float* __restrict__ x, float* __restrict__ mask,
    float* __restrict__ ut2, float* __restrict__ wt2)
{
    if (blockIdx.x >= EMB_BLOCKS) {
        const int eb = blockIdx.x - EMB_BLOCKS;
        const int t  = threadIdx.x;
        if (eb < 96) {                       // U repack
            const int slice = eb >> 3, c = eb & 7;
            const int dir = slice / 6, rem = slice % 6;
            const int g = rem >> 1, kh = rem & 1;
            const int jj = t >> 2, q = t & 3;
            const float* U = dir ? U_b : U_f;
            ut2[(size_t)eb * 256 + t] =
                U[(size_t)(kh * 32 + 4 * c + q) * G3 + g * HID + jj];
        } else {                             // W repack (12 slices x 13 x 64)
            const int slice = eb - 96;
            const int dir = slice / 6, rem = slice % 6;
            const int g = rem >> 1, kh = rem & 1;
            const int ne = kh ? 13 : 12;
            const float* W = dir ? W_b : W_f;
            for (int i = t; i < 13 * 64; i += 256) {
                const int tt = i >> 6, jj = i & 63;
                float v = 0.f;
                if (tt < ne)
                    v = W[(size_t)(kh * 12 + tt) * G3 + g * HID + jj];
                wt2[(size_t)slice * 832 + i] = v;
            }
        }
        return;
    }
    int grp  = blockIdx.x * 8 + (threadIdx.x >> 5);
    int lane = threadIdx.x & 31;
    const int* ids = ids_g + (size_t)grp * TOK;
    float acc = 0.f;
    int cnt = 0;
    #pragma unroll
    for (int t = 0; t < TOK; t++) {
        int id = ids[t];
        if (id != 0) {
            cnt++;
            if (lane < EMB) acc += emb[(size_t)id * EMB + lane];
        }
    }
    if (lane < EMB)
        x[(size_t)grp * EMB + lane] = cnt ? acc / (float)cnt : 0.f;
    if (lane == 0)
        mask[grp] = (ids[0] != 0) ? 1.f : 0.f;
}

// ---------------------------------------------------------------------------
// Kernel 2: GRU scan v4 — 6 waves per (dir,batch-pair): wave=(gate,khalf).
// r7 post-mortem: NB=2 at 3 waves/block halved waves/CU (1.5/SIMD) ->
// latency-bound 530us. v4 keeps NB=2's byte-amortization (each weight load
// feeds 2 batches) but K-splits each gate across 2 waves: 512 blocks x 6
// waves = 12 waves/CU = 3/SIMD (r2's proven occupancy). Weight stream per
// wave-step: 8 coalesced float4 (U k-half) + 13 coalesced dwords (W e-half)
// = 11.25 KB for 2 batches -> 135 KB/CU-step (vs r2's 269) -> BW floor ~2x
// better. Streaming demand ~45 regs: no residency fight, no spill risk.
// Partial channels (z0,z1,r0,r1,hx0,hx1,hr0,hr1) via LDS; waves 4/5 each
// combine ONE batch. 2 lgkm-only barriers/step; stores fire-and-forget;
// x-proj for step+1 in the combine window. Opaque-pinned bases keep loads
// streaming in-loop (validated r6/r7: VGPR 68, FETCH flat).
// ---------------------------------------------------------------------------

#define XPROJ2(PX0, PX1, SROW) do {                                   \
    const float* xr0_ = &xs[0][(SROW) * XPAD];                        \
    const float* xr1_ = &xs[1][(SROW) * XPAD];                        \
    const float* wp_ = wbp;                                           \
    asm volatile("" : "+v"(wp_));                                     \
    const float4* xq0_ = (const float4*)(xr0_ + eoff);                \
    const float4* xq1_ = (const float4*)(xr1_ + eoff);                \
    float q00 = 0.f, q01 = 0.f, q10 = 0.f, q11 = 0.f;                 \
    _Pragma("unroll")                                                 \
    for (int tq = 0; tq < 3; tq++) {                                  \
        const float4 xv0 = xq0_[tq], xv1 = xq1_[tq];                  \
        const float wa_ = wp_[(4 * tq + 0) * 64];                     \
        const float wb_ = wp_[(4 * tq + 1) * 64];                     \
        const float wc_ = wp_[(4 * tq + 2) * 64];                     \
        const float wd_ = wp_[(4 * tq + 3) * 64];                     \
        q00 = fmaf(xv0.x, wa_, q00); q01 = fmaf(xv0.y, wb_, q01);     \
        q00 = fmaf(xv0.z, wc_, q00); q01 = fmaf(xv0.w, wd_, q01);     \
        q10 = fmaf(xv1.x, wa_, q10); q11 = fmaf(xv1.y, wb_, q11);     \
        q10 = fmaf(xv1.z, wc_, q10); q11 = fmaf(xv1.w, wd_, q11);     \
    }                                                                 \
    {   const float w12_ = wp_[12 * 64];                              \
        q00 = fmaf(xr0_[eoff + 12], w12_, q00);                       \
        q10 = fmaf(xr1_[eoff + 12], w12_, q10); }                     \
    PX0 = q00 + q01; PX1 = q10 + q11;                                 \
} while (0)

__global__ __launch_bounds__(384, 2) void gru_kernel(
    const float* __restrict__ xg, const float* __restrict__ maskg,
    const float* __restrict__ b_f, const float* __restrict__ b_b,
    const float* __restrict__ ut2, const float* __restrict__ wt2,
    float* __restrict__ outg, float* __restrict__ hT)
{
    const int bid  = blockIdx.x;
    const int dir  = bid >> 8;         // 0 = forward, 1 = backward
    const int pair = bid & 255;
    const int b0 = pair * 2, b1 = b0 + 1;
    const int tid = threadIdx.x;
    const int w   = tid >> 6;          // wave 0..5
    const int j   = tid & 63;          // hidden column
    const int g   = w >> 1;            // gate: 0=z 1=r 2=h
    const int kh  = w & 1;             // k/e half

    const float* bias = dir ? b_b : b_f;
    const int slice = (dir * 3 + g) * 2 + kh;
    const int eoff  = kh * 12;

    __shared__ __align__(16) float xs[2][SEQ * XPAD];   // 44.8 KB
    __shared__ float ms[2][SEQ];
    __shared__ __align__(16) float hs[2][HID];
    __shared__ float chan[2][8][HID];  // z0 z1 r0 r1 hx0 hx1 hr0 hr1

    // cooperative staging for both batches (coalesced, padded LDS rows)
    for (int i = tid; i < SEQ * EMB; i += 384) {
        int s_ = i / EMB, e_ = i - s_ * EMB;
        xs[0][s_ * XPAD + e_] = xg[(size_t)b0 * (SEQ * EMB) + i];
        xs[1][s_ * XPAD + e_] = xg[(size_t)b1 * (SEQ * EMB) + i];
    }
    for (int i = tid; i < SEQ; i += 384) {
        ms[0][i] = maskg[(size_t)b0 * SEQ + i];
        ms[1][i] = maskg[(size_t)b1 * SEQ + i];
    }
    if (tid < 2 * HID) hs[tid >> 6][tid & 63] = 0.f;

    // combiner-only biases (waves 4/5; z/r merge input+recurrent bias)
    float bZ = 0.f, bR = 0.f, bHX = 0.f, bHR = 0.f;
    if (w >= 4) {
        bZ  = bias[j] + bias[G3 + j];
        bR  = bias[HID + j] + bias[G3 + HID + j];
        bHX = bias[2 * HID + j];
        bHR = bias[G3 + 2 * HID + j];
    }
    __syncthreads();   // staging barrier (vmcnt drain fine, once)

    const float* ub  = ut2 + (size_t)slice * 2048 + j * 4;
    const float* wbp = wt2 + (size_t)slice * 832 + j;

    float h = 0.f;     // running h (each combiner wave: its own batch)
    float* ob = (w >= 4)
        ? outg + (size_t)(b0 + (w - 4)) * SEQ * (2 * HID) + dir * HID + j
        : outg;

    const int sdelta = dir ? -1 : 1;
    int s = dir ? (SEQ - 1) : 0;

    float px0, px1;
    XPROJ2(px0, px1, s);               // prologue: step-0 x-projection

    for (int step = 0; step < SEQ; step++) {
        // recurrent partials, both batches off one coalesced weight stream
        const float* up = ub;
        asm volatile("" : "+v"(up));   // opaque: u-loads stay in-loop
        const float4* h40 = (const float4*)hs[0] + kh * 8;
        const float4* h41 = (const float4*)hs[1] + kh * 8;
        float a0 = 0.f, a1 = 0.f, c0 = 0.f, c1 = 0.f;
        #pragma unroll
        for (int c = 0; c < 8; c++) {
            const float4 u  = *(const float4*)(up + (size_t)c * 256);
            const float4 v0 = h40[c];
            const float4 v1 = h41[c];
            a0 = fmaf(v0.x, u.x, a0);  a1 = fmaf(v0.y, u.y, a1);
            a0 = fmaf(v0.z, u.z, a0);  a1 = fmaf(v0.w, u.w, a1);
            c0 = fmaf(v1.x, u.x, c0);  c1 = fmaf(v1.y, u.y, c1);
            c0 = fmaf(v1.z, u.z, c0);  c1 = fmaf(v1.w, u.w, c1);
        }
        const float ra = a0 + a1, rc = c0 + c1;

        if (g < 2) {
            chan[0][g * 2 + kh][j] = ra + px0;   // z/r: x+rec merged
            chan[1][g * 2 + kh][j] = rc + px1;
        } else {
            chan[0][4 + kh][j] = px0;            // h: keep split
            chan[1][4 + kh][j] = px1;
            chan[0][6 + kh][j] = ra;
            chan[1][6 + kh][j] = rc;
        }

        LDS_BARRIER();   // A: all partials visible

        if (w >= 4) {
            const int cb = w - 4;                // batch index 0/1
            float z  = fast_sigmoid(chan[cb][0][j] + chan[cb][1][j] + bZ);
            float r  = fast_sigmoid(chan[cb][2][j] + chan[cb][3][j] + bR);
            float hx = chan[cb][4][j] + chan[cb][5][j] + bHX;
            float hr = chan[cb][6][j] + chan[cb][7][j] + bHR;
            float hh = fast_tanh(hx + r * hr);
            float hn = z * h + (1.f - z) * hh;
            hn = (ms[cb][s] != 0.f) ? hn : h;
            h = hn;
            hs[cb][j] = hn;
            ob[(size_t)s * (2 * HID)] = hn;      // fire-and-forget
        }

        // x-projection for the NEXT step (h-independent): fills the window
        {
            const int sn = (step < SEQ - 1) ? s + sdelta : s;
            XPROJ2(px0, px1, sn);
            s = sn;
        }

        LDS_BARRIER();   // B: new hs visible to all waves
    }
    if (w >= 4 && dir == 0) hT[(size_t)(b0 + (w - 4)) * HID + j] = h;
}

// ---------------------------------------------------------------------------
// Kernel 3: attention pooling v2 (unchanged from round 6).
// ---------------------------------------------------------------------------

#define WK_LIST(M) \
  M(0)  M(1)  M(2)  M(3)  M(4)  M(5)  M(6)  M(7)  \
  M(8)  M(9)  M(10) M(11) M(12) M(13) M(14) M(15) \
  M(16) M(17) M(18) M(19) M(20) M(21) M(22) M(23) \
  M(24) M(25) M(26) M(27) M(28) M(29) M(30) M(31)

#define DECL_WK(t) const float wk##t = W_k[(size_t)(32 * wave + (t)) * HID + lane];

#define KF4(q, t0, t1, t2, t3) {                  \
    const float4 ov = o4[q];                      \
    acc0 = fmaf(ov.x, wk##t0, acc0);              \
    acc1 = fmaf(ov.y, wk##t1, acc1);              \
    acc0 = fmaf(ov.z, wk##t2, acc0);              \
    acc1 = fmaf(ov.w, wk##t3, acc1); }

__global__ __launch_bounds__(256) void attn_kernel(
    const float* __restrict__ outg, const float* __restrict__ maskg,
    const float* __restrict__ hT,
    const float* __restrict__ W_k, const float* __restrict__ b_k,
    const float* __restrict__ W_q, const float* __restrict__ b_q,
    const float* __restrict__ W_e, const float* __restrict__ b_e,
    float* __restrict__ ctx)
{
    const int b    = blockIdx.x;
    const int tid  = threadIdx.x;
    const int wave = tid >> 6;
    const int lane = tid & 63;

    __shared__ float qs[HID];
    __shared__ float es[SEQ];
    __shared__ __align__(16) float kp[ATILE][4][HID];
    __shared__ __align__(16) float psum[4][2 * HID];

    WK_LIST(DECL_WK)

    const float bkj = b_k[lane];
    const float wej = W_e[lane];
    const float be  = b_e[0];

    if (tid < HID) {
        float q = b_q[tid];
        const float* hrow = hT + (size_t)b * HID;
        #pragma unroll 8
        for (int i = 0; i < HID; i++) q = fmaf(hrow[i], W_q[i * HID + tid], q);
        qs[tid] = q;
    }
    __syncthreads();
    const float qj = qs[lane];

    for (int s0 = 0; s0 < SEQ; s0 += ATILE) {
        #pragma unroll 2
        for (int t = 0; t < ATILE; t++) {
            const int s = s0 + t;
            const float4* o4 = (const float4*)(outg +
                ((size_t)b * SEQ + s) * (2 * HID) + 32 * wave);
            float acc0 = 0.f, acc1 = 0.f;
            KF4(0,  0,  1,  2,  3)  KF4(1,  4,  5,  6,  7)
            KF4(2,  8,  9, 10, 11)  KF4(3, 12, 13, 14, 15)
            KF4(4, 16, 17, 18, 19)  KF4(5, 20, 21, 22, 23)
            KF4(6, 24, 25, 26, 27)  KF4(7, 28, 29, 30, 31)
            kp[t][wave][lane] = acc0 + acc1;
        }
        __syncthreads();
        #pragma unroll
        for (int t = wave; t < ATILE; t += 4) {
            const int s = s0 + t;
            float k = (kp[t][0][lane] + kp[t][1][lane]) +
                      (kp[t][2][lane] + kp[t][3][lane]);
            float v = tanhf(k + bkj + qj) * wej;
            #pragma unroll
            for (int off = 32; off > 0; off >>= 1) v += __shfl_xor(v, off);
            if (lane == 0) {
                float pen = (maskg[(size_t)b * SEQ + s] != 0.f) ? 0.f : -1e9f;
                es[s] = v + be + pen;
            }
        }
        __syncthreads();
    }

    if (tid < 64) {
        float mx = -1e30f;
        for (int s2 = tid; s2 < SEQ; s2 += 64) mx = fmaxf(mx, es[s2]);
        #pragma unroll
        for (int off = 32; off > 0; off >>= 1) mx = fmaxf(mx, __shfl_xor(mx, off));
        float sum = 0.f;
        for (int s2 = tid; s2 < SEQ; s2 += 64) {
            float w = expf(es[s2] - mx);
            es[s2] = w;
            sum += w;
        }
        #pragma unroll
        for (int off = 32; off > 0; off >>= 1) sum += __shfl_xor(sum, off);
        float inv = 1.f / sum;
        for (int s2 = tid; s2 < SEQ; s2 += 64) es[s2] *= inv;
    }
    __syncthreads();

    {
        float a0 = 0.f, a1 = 0.f;
        #pragma unroll 2
        for (int s2 = wave; s2 < SEQ; s2 += 4) {
            const float2 v = *(const float2*)(outg +
                ((size_t)b * SEQ + s2) * (2 * HID) + lane * 2);
            const float wsc = es[s2];
            a0 = fmaf(wsc, v.x, a0);
            a1 = fmaf(wsc, v.y, a1);
        }
        psum[wave][2 * lane]     = a0;
        psum[wave][2 * lane + 1] = a1;
    }
    __syncthreads();
    if (tid < 2 * HID) {
        ctx[(size_t)b * (2 * HID) + tid] =
            (psum[0][tid] + psum[1][tid]) + (psum[2][tid] + psum[3][tid]);
    }
}

// ---------------------------------------------------------------------------
extern "C" void kernel_launch(void* const* d_in, const int* in_sizes, int n_in,
                              void* d_out, int out_size, void* d_ws, size_t ws_size,
                              hipStream_t stream) {
    const int*   ids = (const int*)  d_in[0];
    const float* emb = (const float*)d_in[1];
    const float* W_f = (const float*)d_in[2];
    const float* U_f = (const float*)d_in[3];
    const float* b_f = (const float*)d_in[4];
    const float* W_b = (const float*)d_in[5];
    const float* U_b = (const float*)d_in[6];
    const float* b_b = (const float*)d_in[7];
    const float* W_k = (const float*)d_in[8];
    const float* b_k = (const float*)d_in[9];
    const float* W_q = (const float*)d_in[10];
    const float* b_q = (const float*)d_in[11];
    const float* W_e = (const float*)d_in[12];
    const float* b_e = (const float*)d_in[13];

    float* ws   = (float*)d_ws;
    // workspace layout (floats):
    //   x    : [0, 2'560'000)                 (B*S*E)
    //   mask : [2'560'000, 2'662'400)         (B*S)
    //   out  : [2'662'400, 15'769'600)        (B*S*2H)
    //   hT   : [15'769'600, 15'802'368)       (B*H)
    //   ut2  : [15'802'368, 15'826'944)       (12 slices x 8 x 256)
    //   wt2  : [15'826'944, 15'836'928)       (12 slices x 13 x 64)
    float* x    = ws;
    float* mask = ws + 2560000;
    float* out  = ws + 2662400;
    float* hT   = ws + 15769600;
    float* ut2  = ws + 15802368;
    float* wt2  = ws + 15826944;

    emb_mean_kernel<<<EMB_BLOCKS + RPK_BLOCKS, 256, 0, stream>>>(
        ids, emb, U_f, U_b, W_f, W_b, x, mask, ut2, wt2);
    gru_kernel<<<512, 384, 0, stream>>>(x, mask, b_f, b_b, ut2, wt2,
                                        out, hT);
    attn_kernel<<<BATCH, 256, 0, stream>>>(out, mask, hT, W_k, b_k,
                                           W_q, b_q, W_e, b_e, (float*)d_out);
}

// Round 9
// 501.537 us; speedup vs baseline: 1.4823x; 1.0854x over previous
//
#include <hip/hip_runtime.h>
#include <math.h>

#define BATCH 512
#define SEQ   200
#define TOK   10
#define EMB   25
#define HID   64
#define G3    192   // 3*HID
#define ATILE 8     // attn phase-1 s-tile
#define EMB_BLOCKS ((BATCH * SEQ) / 8)   // 12800
#define RPK_BLOCKS 96                    // U repack: 12 slices x 8 chunks

__device__ __forceinline__ float fast_sigmoid(float t) {
    float e = __expf(-t);
    return __builtin_amdgcn_rcpf(1.f + e);
}
__device__ __forceinline__ float fast_tanh(float t) {
    float e2 = __expf(2.f * t);
    return 1.f - 2.f * __builtin_amdgcn_rcpf(e2 + 1.f);
}

// Barrier that orders LDS producer->consumer WITHOUT draining vmcnt.
#define LDS_BARRIER() do {                                   \
    asm volatile("s_waitcnt lgkmcnt(0)" ::: "memory");       \
    __builtin_amdgcn_s_barrier();                            \
    asm volatile("" ::: "memory");                           \
} while (0)

// ---------------------------------------------------------------------------
// Kernel 1: masked-mean embedding bag + step mask. Trailing 96 blocks repack
// U into per-(dir,gate,khalf) coalesced slices (same ut2 layout as r8):
//  ut2[slice*2048 + c*256 + j*4 + q] = U[(kh*32+4c+q)*G3 + g*64 + j],
//  slice = (dir*3+g)*2+kh.
// ---------------------------------------------------------------------------
__global__ __launch_bounds__(256) void emb_mean_kernel(
    const int* __restrict__ ids_g, const float* __restrict__ emb,
    const float* __restrict__ U_f, const float* __restrict__ U_b,
    float* __restrict__ x, float* __restrict__ mask, float* __restrict__ ut2)
{
    if (blockIdx.x >= EMB_BLOCKS) {
        const int eb = blockIdx.x - EMB_BLOCKS;   // 0..95
        const int slice = eb >> 3, c = eb & 7;
        const int dir = slice / 6, rem = slice % 6;
        const int g = rem >> 1, kh = rem & 1;
        const int t = threadIdx.x;
        const int jj = t >> 2, q = t & 3;
        const float* U = dir ? U_b : U_f;
        ut2[(size_t)eb * 256 + t] =
            U[(size_t)(kh * 32 + 4 * c + q) * G3 + g * HID + jj];
        return;
    }
    int grp  = blockIdx.x * 8 + (threadIdx.x >> 5);
    int lane = threadIdx.x & 31;
    const int* ids = ids_g + (size_t)grp * TOK;
    float acc = 0.f;
    int cnt = 0;
    #pragma unroll
    for (int t = 0; t < TOK; t++) {
        int id = ids[t];
        if (id != 0) {
            cnt++;
            if (lane < EMB) acc += emb[(size_t)id * EMB + lane];
        }
    }
    if (lane < EMB)
        x[(size_t)grp * EMB + lane] = cnt ? acc / (float)cnt : 0.f;
    if (lane == 0)
        mask[grp] = (ids[0] != 0) ? 1.f : 0.f;
}

// ---------------------------------------------------------------------------
// Kernel 1b: x-projection hoisted OUT of the scan (it is h-independent —
// the reference computes xT@W+b[0] before the scan too).
//   xp[(dir*102400 + b*200 + s)*192 + cc] = b_dir[0][cc] + x[b,s,:]@W_dir[:,cc]
// 384 threads: thread t -> (dir = t/192, cc = t%192) owns one output column
// with its 25 weights in registers; 64 rows staged in LDS, read as float4
// broadcasts (rows padded to 28). ~1G FMA total -> ~25 us.
// ---------------------------------------------------------------------------
__global__ __launch_bounds__(384) void xproj_kernel(
    const float* __restrict__ xg,
    const float* __restrict__ W_f, const float* __restrict__ b_f,
    const float* __restrict__ W_b, const float* __restrict__ b_b,
    float* __restrict__ xp)
{
    const int t   = threadIdx.x;          // 0..383
    const int dir = t / G3, cc = t - dir * G3;
    const int gr0 = blockIdx.x * 64;      // first global row (b*200+s)

    __shared__ __align__(16) float xsr[64][28];
    for (int i = t; i < 64 * 28; i += 384) {
        int r = i / 28, e = i - r * 28;
        xsr[r][e] = (e < EMB) ? xg[(size_t)(gr0 + r) * EMB + e] : 0.f;
    }

    const float* W  = dir ? W_b : W_f;
    const float* bb = dir ? b_b : b_f;
    float wreg[28];
    #pragma unroll
    for (int e = 0; e < EMB; e++) wreg[e] = W[(size_t)e * G3 + cc];
    #pragma unroll
    for (int e = EMB; e < 28; e++) wreg[e] = 0.f;
    const float bias = bb[cc];            // input-bias row b[0]

    __syncthreads();

    float* op = xp + ((size_t)(dir * (BATCH * SEQ) + gr0)) * G3 + cc;
    #pragma unroll 4
    for (int r = 0; r < 64; r++) {
        const float4* xv4 = (const float4*)xsr[r];
        float a0 = bias, a1 = 0.f;
        #pragma unroll
        for (int c = 0; c < 7; c++) {
            const float4 xv = xv4[c];
            a0 = fmaf(xv.x, wreg[4 * c + 0], a0);
            a1 = fmaf(xv.y, wreg[4 * c + 1], a1);
            a0 = fmaf(xv.z, wreg[4 * c + 2], a0);
            a1 = fmaf(xv.w, wreg[4 * c + 3], a1);
        }
        op[(size_t)r * G3] = a0 + a1;
    }
}

// ---------------------------------------------------------------------------
// Kernel 2: GRU scan v5 — NB=1, 6 waves = (3 gates x 2 k-halves), ONE
// barrier per step, redundant combine in every wave, wave-private h.
// r8 post-mortem: the scan is STALL-bound (2 barriers + serialized combiner
// wave + in-loop XPROJ; VALUBusy 39%), not weight-BW-bound. v5:
//  - xp precomputed (xproj_kernel) -> no W, no xs, no XPROJ in the loop;
//    kh0 waves stream xp (1 dword/step, prefetched 2 steps ahead).
//  - per-wave U slice = 8 float4 = 32 regs; demand ~52 < the 64-grant
//    ((384,2) measured r8) -> loads hoisted & resident, no pins needed.
//  - every wave computes the full combine from chan partials (identical
//    results in lockstep) and keeps h in its own private hsw[w] copy ->
//    barrier B deleted. chan double-buffered by parity: with one barrier
//    per step, write[p]@step i+2 is separated from read[p]@step i by
//    barrier i+1 -> race-free.
//  - LDS ~6 KB -> 1024 blocks = 4 blocks/CU x 6 waves = 24 waves/CU.
// ---------------------------------------------------------------------------

#define DECL_U4(c) const float4 u##c = \
    *(const float4*)(ut2 + (size_t)slice * 2048 + (c) * 256 + (j << 2));

#define RECC(c) { const float4 hv = hv4[c];              \
    a0 = fmaf(hv.x, u##c.x, a0);                         \
    a1 = fmaf(hv.y, u##c.y, a1);                         \
    a0 = fmaf(hv.z, u##c.z, a0);                         \
    a1 = fmaf(hv.w, u##c.w, a1); }

__global__ __launch_bounds__(384, 2) void gru_kernel(
    const float* __restrict__ xp, const float* __restrict__ maskg,
    const float* __restrict__ b_f, const float* __restrict__ b_b,
    const float* __restrict__ ut2,
    float* __restrict__ outg, float* __restrict__ hT)
{
    const int bid = blockIdx.x;
    const int dir = bid >> 9;          // 0 = forward, 1 = backward
    const int b   = bid & 511;
    const int tid = threadIdx.x;
    const int w   = tid >> 6;          // wave 0..5
    const int j   = tid & 63;          // hidden column
    const int g   = w >> 1;            // gate: 0=z 1=r 2=h
    const int kh  = w & 1;             // k-half
    const int slice = (dir * 3 + g) * 2 + kh;
    const int row   = (g < 2) ? (g * 2 + kh) : (4 + kh);
    const bool hxw  = (g == 2 && kh == 0);

    __shared__ float ms[SEQ];
    __shared__ __align__(16) float hsw[6][HID];    // per-wave private h
    __shared__ float chan[2][7][HID];              // parity-double-buffered

    if (tid < SEQ) ms[tid] = maskg[(size_t)b * SEQ + tid];
    hsw[w][j] = 0.f;

    // resident weights: 8 float4 (32 VGPRs), loop-invariant, demand < grant
    DECL_U4(0) DECL_U4(1) DECL_U4(2) DECL_U4(3)
    DECL_U4(4) DECL_U4(5) DECL_U4(6) DECL_U4(7)

    const float* bias = dir ? b_b : b_f;
    const float b1 = (kh == 0) ? bias[G3 + g * HID + j] : 0.f;  // recurrent bias

    __syncthreads();   // staging barrier (vmcnt drain fine, once)

    // xp stream for this wave's gate column (kh0 waves only), prefetch depth 2
    const float* xpw = xp + ((size_t)(dir * (BATCH * SEQ) + b * SEQ)) * G3
                          + g * HID + j;
    const int sd = dir ? -1 : 1;
    int s = dir ? (SEQ - 1) : 0;
    float x0 = 0.f, x1 = 0.f;
    if (kh == 0) {
        x0 = xpw[(size_t)s * G3];
        x1 = xpw[(size_t)(s + sd) * G3];
    }

    float h = 0.f;
    float* ob = outg + (size_t)b * SEQ * (2 * HID) + dir * HID + j;
    int p = 0;

    for (int step = 0; step < SEQ; step++) {
        float* chp = &chan[p][0][0];

        // recurrent partial from OWN private h copy (broadcast b128 reads)
        const float4* hv4 = (const float4*)&hsw[w][kh * 32];
        float a0 = 0.f, a1 = 0.f;
        RECC(0) RECC(1) RECC(2) RECC(3) RECC(4) RECC(5) RECC(6) RECC(7)
        float part = a0 + a1;
        if (kh == 0) part += b1 + ((g < 2) ? x0 : 0.f);  // z/r: merge xp here
        chp[row * HID + j] = part;
        if (hxw) chp[6 * HID + j] = x0;                  // xh kept separate

        // prefetch xp two steps ahead (HBM-latency proof)
        float x2 = 0.f;
        if (kh == 0) {
            int ip = s + 2 * sd;
            ip = ip < 0 ? 0 : (ip > SEQ - 1 ? SEQ - 1 : ip);
            x2 = xpw[(size_t)ip * G3];
        }

        LDS_BARRIER();   // the ONLY barrier per step

        // redundant combine: every wave, identical result (lockstep fp)
        {
            float z  = fast_sigmoid(chp[0 * HID + j] + chp[1 * HID + j]);
            float r  = fast_sigmoid(chp[2 * HID + j] + chp[3 * HID + j]);
            float rh =              chp[4 * HID + j] + chp[5 * HID + j];
            float hh = fast_tanh(chp[6 * HID + j] + r * rh);
            float hn = z * h + (1.f - z) * hh;
            hn = (ms[s] != 0.f) ? hn : h;
            h = hn;
            hsw[w][j] = hn;                       // own private copy
            if (w == 0) ob[(size_t)s * (2 * HID)] = hn;   // fire-and-forget
        }

        x0 = x1; x1 = x2;
        s += sd;
        p ^= 1;
    }
    if (w == 0 && dir == 0) hT[(size_t)b * HID + j] = h;
}

// ---------------------------------------------------------------------------
// Kernel 3: attention pooling v2 (unchanged from round 6).
// ---------------------------------------------------------------------------

#define WK_LIST(M) \
  M(0)  M(1)  M(2)  M(3)  M(4)  M(5)  M(6)  M(7)  \
  M(8)  M(9)  M(10) M(11) M(12) M(13) M(14) M(15) \
  M(16) M(17) M(18) M(19) M(20) M(21) M(22) M(23) \
  M(24) M(25) M(26) M(27) M(28) M(29) M(30) M(31)

#define DECL_WK(t) const float wk##t = W_k[(size_t)(32 * wave + (t)) * HID + lane];

#define KF4(q, t0, t1, t2, t3) {                  \
    const float4 ov = o4[q];                      \
    acc0 = fmaf(ov.x, wk##t0, acc0);              \
    acc1 = fmaf(ov.y, wk##t1, acc1);              \
    acc0 = fmaf(ov.z, wk##t2, acc0);              \
    acc1 = fmaf(ov.w, wk##t3, acc1); }

__global__ __launch_bounds__(256) void attn_kernel(
    const float* __restrict__ outg, const float* __restrict__ maskg,
    const float* __restrict__ hT,
    const float* __restrict__ W_k, const float* __restrict__ b_k,
    const float* __restrict__ W_q, const float* __restrict__ b_q,
    const float* __restrict__ W_e, const float* __restrict__ b_e,
    float* __restrict__ ctx)
{
    const int b    = blockIdx.x;
    const int tid  = threadIdx.x;
    const int wave = tid >> 6;
    const int lane = tid & 63;

    __shared__ float qs[HID];
    __shared__ float es[SEQ];
    __shared__ __align__(16) float kp[ATILE][4][HID];
    __shared__ __align__(16) float psum[4][2 * HID];

    WK_LIST(DECL_WK)

    const float bkj = b_k[lane];
    const float wej = W_e[lane];
    const float be  = b_e[0];

    if (tid < HID) {
        float q = b_q[tid];
        const float* hrow = hT + (size_t)b * HID;
        #pragma unroll 8
        for (int i = 0; i < HID; i++) q = fmaf(hrow[i], W_q[i * HID + tid], q);
        qs[tid] = q;
    }
    __syncthreads();
    const float qj = qs[lane];

    for (int s0 = 0; s0 < SEQ; s0 += ATILE) {
        #pragma unroll 2
        for (int t = 0; t < ATILE; t++) {
            const int s = s0 + t;
            const float4* o4 = (const float4*)(outg +
                ((size_t)b * SEQ + s) * (2 * HID) + 32 * wave);
            float acc0 = 0.f, acc1 = 0.f;
            KF4(0,  0,  1,  2,  3)  KF4(1,  4,  5,  6,  7)
            KF4(2,  8,  9, 10, 11)  KF4(3, 12, 13, 14, 15)
            KF4(4, 16, 17, 18, 19)  KF4(5, 20, 21, 22, 23)
            KF4(6, 24, 25, 26, 27)  KF4(7, 28, 29, 30, 31)
            kp[t][wave][lane] = acc0 + acc1;
        }
        __syncthreads();
        #pragma unroll
        for (int t = wave; t < ATILE; t += 4) {
            const int s = s0 + t;
            float k = (kp[t][0][lane] + kp[t][1][lane]) +
                      (kp[t][2][lane] + kp[t][3][lane]);
            float v = tanhf(k + bkj + qj) * wej;
            #pragma unroll
            for (int off = 32; off > 0; off >>= 1) v += __shfl_xor(v, off);
            if (lane == 0) {
                float pen = (maskg[(size_t)b * SEQ + s] != 0.f) ? 0.f : -1e9f;
                es[s] = v + be + pen;
            }
        }
        __syncthreads();
    }

    if (tid < 64) {
        float mx = -1e30f;
        for (int s2 = tid; s2 < SEQ; s2 += 64) mx = fmaxf(mx, es[s2]);
        #pragma unroll
        for (int off = 32; off > 0; off >>= 1) mx = fmaxf(mx, __shfl_xor(mx, off));
        float sum = 0.f;
        for (int s2 = tid; s2 < SEQ; s2 += 64) {
            float w = expf(es[s2] - mx);
            es[s2] = w;
            sum += w;
        }
        #pragma unroll
        for (int off = 32; off > 0; off >>= 1) sum += __shfl_xor(sum, off);
        float inv = 1.f / sum;
        for (int s2 = tid; s2 < SEQ; s2 += 64) es[s2] *= inv;
    }
    __syncthreads();

    {
        float a0 = 0.f, a1 = 0.f;
        #pragma unroll 2
        for (int s2 = wave; s2 < SEQ; s2 += 4) {
            const float2 v = *(const float2*)(outg +
                ((size_t)b * SEQ + s2) * (2 * HID) + lane * 2);
            const float wsc = es[s2];
            a0 = fmaf(wsc, v.x, a0);
            a1 = fmaf(wsc, v.y, a1);
        }
        psum[wave][2 * lane]     = a0;
        psum[wave][2 * lane + 1] = a1;
    }
    __syncthreads();
    if (tid < 2 * HID) {
        ctx[(size_t)b * (2 * HID) + tid] =
            (psum[0][tid] + psum[1][tid]) + (psum[2][tid] + psum[3][tid]);
    }
}

// ---------------------------------------------------------------------------
extern "C" void kernel_launch(void* const* d_in, const int* in_sizes, int n_in,
                              void* d_out, int out_size, void* d_ws, size_t ws_size,
                              hipStream_t stream) {
    const int*   ids = (const int*)  d_in[0];
    const float* emb = (const float*)d_in[1];
    const float* W_f = (const float*)d_in[2];
    const float* U_f = (const float*)d_in[3];
    const float* b_f = (const float*)d_in[4];
    const float* W_b = (const float*)d_in[5];
    const float* U_b = (const float*)d_in[6];
    const float* b_b = (const float*)d_in[7];
    const float* W_k = (const float*)d_in[8];
    const float* b_k = (const float*)d_in[9];
    const float* W_q = (const float*)d_in[10];
    const float* b_q = (const float*)d_in[11];
    const float* W_e = (const float*)d_in[12];
    const float* b_e = (const float*)d_in[13];

    float* ws   = (float*)d_ws;
    // workspace layout (floats):
    //   x    : [0, 2'560'000)                  (B*S*E)
    //   mask : [2'560'000, 2'662'400)          (B*S)
    //   out  : [2'662'400, 15'769'600)         (B*S*2H)
    //   hT   : [15'769'600, 15'802'368)        (B*H)
    //   ut2  : [15'802'368, 15'826'944)        (12 slices x 8 x 256)
    //   xp   : [15'826'944, 55'148'544)        (2*B*S*192) = 157 MB
    float* x    = ws;
    float* mask = ws + 2560000;
    float* out  = ws + 2662400;
    float* hT   = ws + 15769600;
    float* ut2  = ws + 15802368;
    float* xp   = ws + 15826944;

    emb_mean_kernel<<<EMB_BLOCKS + RPK_BLOCKS, 256, 0, stream>>>(
        ids, emb, U_f, U_b, x, mask, ut2);
    xproj_kernel<<<(BATCH * SEQ) / 64, 384, 0, stream>>>(
        x, W_f, b_f, W_b, b_b, xp);
    gru_kernel<<<1024, 384, 0, stream>>>(xp, mask, b_f, b_b, ut2, out, hT);
    attn_kernel<<<BATCH, 256, 0, stream>>>(out, mask, hT, W_k, b_k,
                                           W_q, b_q, W_e, b_e, (float*)d_out);
}